// Round 3
// baseline (604.654 us; speedup 1.0000x reference)
//
#include <hip/hip_runtime.h>
#include <cmath>

#define NC 192   // H*C
#define CC 64
#define DOUTK 16

__device__ __forceinline__ float lrelu(float x) { return x > 0.f ? x : 0.2f * x; }

__device__ __forceinline__ float wred_sum(float v) {
#pragma unroll
  for (int off = 32; off; off >>= 1) v += __shfl_xor(v, off);
  return v;
}
__device__ __forceinline__ float wred_max(float v) {
#pragma unroll
  for (int off = 32; off; off >>= 1) v = fmaxf(v, __shfl_xor(v, off));
  return v;
}
// reduce within 32-lane half-wave
__device__ __forceinline__ float hred_sum(float v) {
#pragma unroll
  for (int off = 16; off; off >>= 1) v += __shfl_xor(v, off);
  return v;
}

// ---------------- CSR build (dst-sorted) ----------------
__global__ void k_hist(const int* __restrict__ dsts, int* __restrict__ deg, int E) {
  int e = blockIdx.x * 256 + threadIdx.x;
  if (e < E) atomicAdd(&deg[dsts[e]], 1);
}

__global__ void k_scan_block(const int* __restrict__ deg, int* __restrict__ rowptr,
                             int* __restrict__ bsum, int Nn) {
  __shared__ int tmp[256];
  int i = blockIdx.x * 256 + threadIdx.x;
  int v = (i < Nn) ? deg[i] : 0;
  tmp[threadIdx.x] = v;
  __syncthreads();
  for (int off = 1; off < 256; off <<= 1) {
    int t = (threadIdx.x >= off) ? tmp[threadIdx.x - off] : 0;
    __syncthreads();
    tmp[threadIdx.x] += t;
    __syncthreads();
  }
  if (i < Nn) rowptr[i] = tmp[threadIdx.x] - v;   // exclusive
  if (threadIdx.x == 255) bsum[blockIdx.x] = tmp[255];
}

__global__ void k_scan_bsum(int* __restrict__ bsum, int B) {
  __shared__ int tmp[256];
  int v = (threadIdx.x < B) ? bsum[threadIdx.x] : 0;
  tmp[threadIdx.x] = v;
  __syncthreads();
  for (int off = 1; off < 256; off <<= 1) {
    int t = (threadIdx.x >= off) ? tmp[threadIdx.x - off] : 0;
    __syncthreads();
    tmp[threadIdx.x] += t;
    __syncthreads();
  }
  if (threadIdx.x < B) bsum[threadIdx.x] = tmp[threadIdx.x] - v;  // exclusive
}

__global__ void k_add_off(int* __restrict__ rowptr, const int* __restrict__ bsum,
                          int* __restrict__ cursor, int Nn) {
  int i = blockIdx.x * 256 + threadIdx.x;
  if (i < Nn) {
    int r = rowptr[i] + bsum[blockIdx.x];
    rowptr[i] = r;
    cursor[i] = r;
  }
}

__global__ void k_scatter(const int* __restrict__ srcs, const int* __restrict__ dsts,
                          int* __restrict__ cursor, int* __restrict__ csr_src, int E) {
  int e = blockIdx.x * 256 + threadIdx.x;
  if (e < E) {
    int d = dsts[e];
    int p = atomicAdd(&cursor[d], 1);
    csr_src[p] = srcs[e];
  }
}

// ---------------- GEMM + fused attention scores (no LDS) ----------------
// XW[M,192] = X[M,K] @ W[K,192]. Block = 256 thr = 4 waves, 64 rows/block.
// Each wave: 16 rows, split into two 32-lane halves of 8 rows each.
// Lane (li = lane&31) owns 6 cols: {h*64 + li*2, +1} for h=0..2.
// x reads: wave-uniform-per-half float4 broadcasts (L1-resident, no LDS).
// W reads: 32-lane coalesced float2 (L2-resident). 192 FMA / 20 VMEM per 4-k chunk.
template<int K, bool GUARD>
__device__ __forceinline__ void gemm_body(
    const float* __restrict__ X, const float* __restrict__ W,
    const float* __restrict__ att_src, const float* __restrict__ att_dst,
    float* __restrict__ XW, float* __restrict__ asrc, float* __restrict__ adst,
    int M, int row0, int li) {
  float acc[8][6];
#pragma unroll
  for (int r = 0; r < 8; ++r)
#pragma unroll
    for (int c = 0; c < 6; ++c) acc[r][c] = 0.f;

  for (int kk = 0; kk < K; kk += 4) {
    float4 xv[8];
#pragma unroll
    for (int r = 0; r < 8; ++r) {
      if (GUARD && row0 + r >= M) xv[r] = make_float4(0.f, 0.f, 0.f, 0.f);
      else xv[r] = *(const float4*)&X[(size_t)(row0 + r) * K + kk];
    }
    float2 w[4][3];
#pragma unroll
    for (int j = 0; j < 4; ++j)
#pragma unroll
      for (int h = 0; h < 3; ++h)
        w[j][h] = *(const float2*)&W[(size_t)(kk + j) * NC + h * 64 + li * 2];
#pragma unroll
    for (int r = 0; r < 8; ++r)
#pragma unroll
      for (int h = 0; h < 3; ++h) {
        acc[r][h * 2]     += xv[r].x * w[0][h].x + xv[r].y * w[1][h].x +
                             xv[r].z * w[2][h].x + xv[r].w * w[3][h].x;
        acc[r][h * 2 + 1] += xv[r].x * w[0][h].y + xv[r].y * w[1][h].y +
                             xv[r].z * w[2][h].y + xv[r].w * w[3][h].y;
      }
  }

  float2 avs[3], avd[3];
#pragma unroll
  for (int h = 0; h < 3; ++h) {
    avs[h] = *(const float2*)&att_src[h * 64 + li * 2];
    avd[h] = *(const float2*)&att_dst[h * 64 + li * 2];
  }
#pragma unroll
  for (int r = 0; r < 8; ++r) {
    int row = row0 + r;
    if (GUARD && row >= M) break;
    float sh[3], dh[3];
#pragma unroll
    for (int h = 0; h < 3; ++h) {
      sh[h] = hred_sum(acc[r][h * 2] * avs[h].x + acc[r][h * 2 + 1] * avs[h].y);
      dh[h] = hred_sum(acc[r][h * 2] * avd[h].x + acc[r][h * 2 + 1] * avd[h].y);
      *(float2*)&XW[(size_t)row * NC + h * 64 + li * 2] =
          make_float2(acc[r][h * 2], acc[r][h * 2 + 1]);
    }
    if (li == 0) {
#pragma unroll
      for (int h = 0; h < 3; ++h) {
        asrc[row * 3 + h] = sh[h];
        adst[row * 3 + h] = dh[h];
      }
    }
  }
}

template<int K>
__global__ __launch_bounds__(256) void k_gemm_att(
    const float* __restrict__ X, const float* __restrict__ W,
    const float* __restrict__ att_src, const float* __restrict__ att_dst,
    float* __restrict__ XW, float* __restrict__ asrc, float* __restrict__ adst, int M) {
  const int tid = threadIdx.x;
  const int wv = tid >> 6;
  const int lane = tid & 63;
  const int half = lane >> 5;
  const int li = lane & 31;
  const int row0 = blockIdx.x * 64 + wv * 16 + half * 8;
  if (row0 + 8 <= M)
    gemm_body<K, false>(X, W, att_src, att_dst, XW, asrc, adst, M, row0, li);
  else
    gemm_body<K, true>(X, W, att_src, att_dst, XW, asrc, adst, M, row0, li);
}

// ---------------- fused segment-softmax + aggregation, one wave per node ----------------
template<bool RELU>
__global__ __launch_bounds__(256) void k_aggregate(
    const float* __restrict__ xw, const float* __restrict__ asrc,
    const float* __restrict__ adst, const int* __restrict__ rowptr,
    const int* __restrict__ deg, const int* __restrict__ csr_src,
    const float* __restrict__ bias, float* __restrict__ out, int Nn) {
  int wid = threadIdx.x >> 6, lane = threadIdx.x & 63;
  int n = blockIdx.x * 4 + wid;
  if (n >= Nn) return;
  int row = rowptr[n], d = deg[n];
  float ad0 = adst[n * 3], ad1 = adst[n * 3 + 1], ad2 = adst[n * 3 + 2];
  float sa0 = lrelu(asrc[n * 3] + ad0);       // self-loop alpha
  float sa1 = lrelu(asrc[n * 3 + 1] + ad1);
  float sa2 = lrelu(asrc[n * 3 + 2] + ad2);

  float acc0, acc1, acc2, S0, S1, S2;

  if (d <= 64) {
    // fast path: lane e owns edge e; alpha computed exactly once per edge
    int s = 0;
    float al0 = -INFINITY, al1 = -INFINITY, al2 = -INFINITY;
    if (lane < d) {
      s = csr_src[row + lane];
      al0 = lrelu(asrc[s * 3] + ad0);
      al1 = lrelu(asrc[s * 3 + 1] + ad1);
      al2 = lrelu(asrc[s * 3 + 2] + ad2);
    }
    float m0 = fmaxf(wred_max(al0), sa0);
    float m1 = fmaxf(wred_max(al1), sa1);
    float m2 = fmaxf(wred_max(al2), sa2);
    float w0 = __expf(al0 - m0);   // inactive lanes: exp(-inf)=0
    float w1 = __expf(al1 - m1);
    float w2 = __expf(al2 - m2);
    float e0 = __expf(sa0 - m0), e1 = __expf(sa1 - m1), e2 = __expf(sa2 - m2);
    S0 = wred_sum(w0) + e0 + 1e-16f;
    S1 = wred_sum(w1) + e1 + 1e-16f;
    S2 = wred_sum(w2) + e2 + 1e-16f;
    // weighted gather: lane = channel, broadcast edge weight/src via shfl
    const float* xrs = xw + (size_t)n * NC;
    acc0 = e0 * xrs[lane];
    acc1 = e1 * xrs[64 + lane];
    acc2 = e2 * xrs[128 + lane];
    for (int e = 0; e < d; ++e) {
      int se = __shfl(s, e);
      float we0 = __shfl(w0, e), we1 = __shfl(w1, e), we2 = __shfl(w2, e);
      const float* xr = xw + (size_t)se * NC;
      acc0 += we0 * xr[lane];
      acc1 += we1 * xr[64 + lane];
      acc2 += we2 * xr[128 + lane];
    }
  } else {
    // slow path (d > 64): 3-pass, lane-strided
    float m0 = sa0, m1 = sa1, m2 = sa2;
    for (int e = lane; e < d; e += 64) {
      int s = csr_src[row + e];
      m0 = fmaxf(m0, lrelu(asrc[s * 3] + ad0));
      m1 = fmaxf(m1, lrelu(asrc[s * 3 + 1] + ad1));
      m2 = fmaxf(m2, lrelu(asrc[s * 3 + 2] + ad2));
    }
    m0 = wred_max(m0); m1 = wred_max(m1); m2 = wred_max(m2);
    float p0 = 0.f, p1 = 0.f, p2 = 0.f;
    for (int e = lane; e < d; e += 64) {
      int s = csr_src[row + e];
      p0 += __expf(lrelu(asrc[s * 3] + ad0) - m0);
      p1 += __expf(lrelu(asrc[s * 3 + 1] + ad1) - m1);
      p2 += __expf(lrelu(asrc[s * 3 + 2] + ad2) - m2);
    }
    S0 = wred_sum(p0) + __expf(sa0 - m0) + 1e-16f;
    S1 = wred_sum(p1) + __expf(sa1 - m1) + 1e-16f;
    S2 = wred_sum(p2) + __expf(sa2 - m2) + 1e-16f;
    const float* xrs = xw + (size_t)n * NC;
    acc0 = __expf(sa0 - m0) * xrs[lane];
    acc1 = __expf(sa1 - m1) * xrs[64 + lane];
    acc2 = __expf(sa2 - m2) * xrs[128 + lane];
    for (int e = 0; e < d; ++e) {
      int s = csr_src[row + e];
      float we0 = __expf(lrelu(asrc[s * 3] + ad0) - m0);
      float we1 = __expf(lrelu(asrc[s * 3 + 1] + ad1) - m1);
      float we2 = __expf(lrelu(asrc[s * 3 + 2] + ad2) - m2);
      const float* xr = xw + (size_t)s * NC;
      acc0 += we0 * xr[lane];
      acc1 += we1 * xr[64 + lane];
      acc2 += we2 * xr[128 + lane];
    }
  }

  float o = (acc0 / S0 + acc1 / S1 + acc2 / S2) * (1.f / 3.f) + bias[lane];
  out[(size_t)n * CC + lane] = RELU ? fmaxf(o, 0.f) : o;
}

// ---------------- final linear: logit[N,16] = h[N,64] @ Wl[64,16] + bl ----------------
__global__ void k_logit(const float* __restrict__ h, const float* __restrict__ Wl,
                        const float* __restrict__ bl, float* __restrict__ out, int Nn) {
  __shared__ float wl_s[CC * DOUTK];
  __shared__ float hrow[4][CC];
  int tid = threadIdx.x;
  for (int i = tid; i < CC * DOUTK; i += 256) wl_s[i] = Wl[i];
  int wid = tid >> 6, lane = tid & 63;
  int n = blockIdx.x * 4 + wid;
  if (n < Nn) hrow[wid][lane] = h[(size_t)n * CC + lane];
  __syncthreads();
  if (n < Nn && lane < DOUTK) {
    float acc = bl[lane];
#pragma unroll
    for (int c = 0; c < CC; ++c) acc += hrow[wid][c] * wl_s[c * DOUTK + lane];
    out[(size_t)n * DOUTK + lane] = acc;
  }
}

extern "C" void kernel_launch(void* const* d_in, const int* in_sizes, int n_in,
                              void* d_out, int out_size, void* d_ws, size_t ws_size,
                              hipStream_t stream) {
  const float* x   = (const float*)d_in[0];
  const float* W1  = (const float*)d_in[1];
  const float* as1 = (const float*)d_in[2];
  const float* ad1 = (const float*)d_in[3];
  const float* b1  = (const float*)d_in[4];
  const float* W2  = (const float*)d_in[5];
  const float* as2 = (const float*)d_in[6];
  const float* ad2 = (const float*)d_in[7];
  const float* b2  = (const float*)d_in[8];
  const float* Wl  = (const float*)d_in[9];
  const float* bl  = (const float*)d_in[10];
  const int* edges = (const int*)d_in[11];

  const int Nn = in_sizes[0] / 256;   // 50000
  const int E  = in_sizes[11] / 2;    // 800000
  const int* srcs = edges;
  const int* dsts = edges + E;

  float* out_logit = (float*)d_out;                       // [N,16]
  float* out_h     = (float*)d_out + (size_t)Nn * DOUTK;  // [N,64]

  char* p = (char*)d_ws;
  auto alloc = [&](size_t bytes) {
    char* r = p;
    p += (bytes + 255) & ~(size_t)255;
    return r;
  };
  float* xw    = (float*)alloc((size_t)Nn * NC * 4);
  float* h1    = (float*)alloc((size_t)Nn * CC * 4);
  float* asrc  = (float*)alloc((size_t)Nn * 3 * 4);
  float* adst  = (float*)alloc((size_t)Nn * 3 * 4);
  int* deg     = (int*)alloc((size_t)Nn * 4);
  int* rowptr  = (int*)alloc((size_t)Nn * 4);
  int* cursor  = (int*)alloc((size_t)Nn * 4);
  int* bsum    = (int*)alloc(256 * 4);
  int* csr_src = (int*)alloc((size_t)E * 4);

  const int nB = (Nn + 255) / 256;   // 196 (<=256 required by k_scan_bsum)
  const int eB = (E + 255) / 256;
  const int gB = (Nn + 63) / 64;
  const int aB = (Nn + 3) / 4;

  // CSR build (ws is re-poisoned every call -> rebuild everything)
  hipMemsetAsync(deg, 0, (size_t)Nn * 4, stream);
  k_hist<<<eB, 256, 0, stream>>>(dsts, deg, E);
  k_scan_block<<<nB, 256, 0, stream>>>(deg, rowptr, bsum, Nn);
  k_scan_bsum<<<1, 256, 0, stream>>>(bsum, nB);
  k_add_off<<<nB, 256, 0, stream>>>(rowptr, bsum, cursor, Nn);
  k_scatter<<<eB, 256, 0, stream>>>(srcs, dsts, cursor, csr_src, E);

  // layer 1 (att scores fused into GEMM epilogue)
  k_gemm_att<256><<<gB, 256, 0, stream>>>(x, W1, as1, ad1, xw, asrc, adst, Nn);
  k_aggregate<true><<<aB, 256, 0, stream>>>(xw, asrc, adst, rowptr, deg, csr_src, b1, h1, Nn);

  // layer 2
  k_gemm_att<64><<<gB, 256, 0, stream>>>(h1, W2, as2, ad2, xw, asrc, adst, Nn);
  k_aggregate<false><<<aB, 256, 0, stream>>>(xw, asrc, adst, rowptr, deg, csr_src, b2, out_h, Nn);

  // final linear
  k_logit<<<aB, 256, 0, stream>>>(out_h, Wl, bl, out_logit, Nn);
}

// Round 4
// 506.046 us; speedup vs baseline: 1.1949x; 1.1949x over previous
//
#include <hip/hip_runtime.h>
#include <cmath>

#define NC 192   // H*C
#define CC 64
#define DOUTK 16

typedef _Float16 f16x8 __attribute__((ext_vector_type(8)));
typedef _Float16 f16x4 __attribute__((ext_vector_type(4)));
typedef float f32x4 __attribute__((ext_vector_type(4)));

__device__ __forceinline__ float lrelu(float x) { return x > 0.f ? x : 0.2f * x; }

__device__ __forceinline__ float wred_sum(float v) {
#pragma unroll
  for (int off = 32; off; off >>= 1) v += __shfl_xor(v, off);
  return v;
}
__device__ __forceinline__ float wred_max(float v) {
#pragma unroll
  for (int off = 32; off; off >>= 1) v = fmaxf(v, __shfl_xor(v, off));
  return v;
}

// ---------------- CSR build (dst-sorted) ----------------
__global__ void k_hist(const int* __restrict__ dsts, int* __restrict__ deg, int E) {
  int e = blockIdx.x * 256 + threadIdx.x;
  if (e < E) atomicAdd(&deg[dsts[e]], 1);
}

__global__ void k_scan_block(const int* __restrict__ deg, int* __restrict__ rowptr,
                             int* __restrict__ bsum, int Nn) {
  __shared__ int tmp[256];
  int i = blockIdx.x * 256 + threadIdx.x;
  int v = (i < Nn) ? deg[i] : 0;
  tmp[threadIdx.x] = v;
  __syncthreads();
  for (int off = 1; off < 256; off <<= 1) {
    int t = (threadIdx.x >= off) ? tmp[threadIdx.x - off] : 0;
    __syncthreads();
    tmp[threadIdx.x] += t;
    __syncthreads();
  }
  if (i < Nn) rowptr[i] = tmp[threadIdx.x] - v;   // exclusive
  if (threadIdx.x == 255) bsum[blockIdx.x] = tmp[255];
}

__global__ void k_scan_bsum(int* __restrict__ bsum, int B) {
  __shared__ int tmp[256];
  int v = (threadIdx.x < B) ? bsum[threadIdx.x] : 0;
  tmp[threadIdx.x] = v;
  __syncthreads();
  for (int off = 1; off < 256; off <<= 1) {
    int t = (threadIdx.x >= off) ? tmp[threadIdx.x - off] : 0;
    __syncthreads();
    tmp[threadIdx.x] += t;
    __syncthreads();
  }
  if (threadIdx.x < B) bsum[threadIdx.x] = tmp[threadIdx.x] - v;  // exclusive
}

__global__ void k_add_off(int* __restrict__ rowptr, const int* __restrict__ bsum,
                          int* __restrict__ cursor, int Nn) {
  int i = blockIdx.x * 256 + threadIdx.x;
  if (i < Nn) {
    int r = rowptr[i] + bsum[blockIdx.x];
    rowptr[i] = r;
    cursor[i] = r;
  }
}

__global__ void k_scatter(const int* __restrict__ srcs, const int* __restrict__ dsts,
                          int* __restrict__ cursor, int* __restrict__ csr_src, int E) {
  int e = blockIdx.x * 256 + threadIdx.x;
  if (e < E) {
    int d = dsts[e];
    int p = atomicAdd(&cursor[d], 1);
    csr_src[p] = srcs[e];
  }
}

// ---------------- dtype conversion ----------------
__global__ void k_f2h(const float* __restrict__ in, _Float16* __restrict__ out, int n4) {
  int i = blockIdx.x * 256 + threadIdx.x;
  if (i < n4) {
    float4 v = *(const float4*)(in + (size_t)i * 4);
    f16x4 o;
    o[0] = (_Float16)v.x; o[1] = (_Float16)v.y;
    o[2] = (_Float16)v.z; o[3] = (_Float16)v.w;
    *(f16x4*)(out + (size_t)i * 4) = o;
  }
}

// W[K][192] fp32 -> WT[192][K] fp16
__global__ void k_wT(const float* __restrict__ W, _Float16* __restrict__ WT, int K) {
  int i = blockIdx.x * 256 + threadIdx.x;
  if (i < NC * K) {
    int c = i / K, k = i - c * K;
    WT[i] = (_Float16)W[(size_t)k * NC + c];
  }
}

// ---------------- MFMA GEMM + fused attention scores ----------------
// XW[M,192] = A[M,K](f16) @ WT[192,K]^T. Block=256thr=4 waves; wave: 16 rows x 192 cols.
// 12 x mfma_f32_16x16x32_f16 per k-step. A frag: row l&15, k=(l>>4)*8.. (16B coalesced,
// read-once). B frag: col l&15 from WT (L2-resident, 12 independent 16B loads/step).
// D layout (m89): col=lane&15, row=(lane>>4)*4+reg.
template<int K>
__global__ __launch_bounds__(256) void k_gemm_mfma_att(
    const _Float16* __restrict__ A, const _Float16* __restrict__ WT,
    const float* __restrict__ att_src, const float* __restrict__ att_dst,
    float* __restrict__ XW, float* __restrict__ asrc, float* __restrict__ adst, int M) {
  const int lane = threadIdx.x & 63;
  const int wv = threadIdx.x >> 6;
  const int li = lane & 15;
  const int g  = lane >> 4;
  const int row0 = blockIdx.x * 64 + wv * 16;
  if (row0 >= M) return;   // M % 16 == 0: waves are all-valid or all-out

  f32x4 acc[12];
#pragma unroll
  for (int t = 0; t < 12; ++t) acc[t] = (f32x4){0.f, 0.f, 0.f, 0.f};

  const _Float16* arow = A + (size_t)(row0 + li) * K + g * 8;

  for (int s = 0; s < K / 32; ++s) {
    f16x8 af = *(const f16x8*)(arow + s * 32);
#pragma unroll
    for (int t = 0; t < 12; ++t) {
      f16x8 bf = *(const f16x8*)(WT + (size_t)(t * 16 + li) * K + s * 32 + g * 8);
      acc[t] = __builtin_amdgcn_mfma_f32_16x16x32_f16(af, bf, acc[t], 0, 0, 0);
    }
  }

  // store XW (fp32)
#pragma unroll
  for (int t = 0; t < 12; ++t)
#pragma unroll
    for (int r = 0; r < 4; ++r)
      XW[(size_t)(row0 + g * 4 + r) * NC + t * 16 + li] = acc[t][r];

  // fused attention scores: per head h, per row: sum over 64 cols = 4 tiles x 16 lanes
  float avs[12], avd[12];
#pragma unroll
  for (int t = 0; t < 12; ++t) {
    avs[t] = att_src[t * 16 + li];   // att_src flat [192]
    avd[t] = att_dst[t * 16 + li];
  }
#pragma unroll
  for (int h = 0; h < 3; ++h)
#pragma unroll
    for (int r = 0; r < 4; ++r) {
      float s = acc[4 * h][r] * avs[4 * h] + acc[4 * h + 1][r] * avs[4 * h + 1] +
                acc[4 * h + 2][r] * avs[4 * h + 2] + acc[4 * h + 3][r] * avs[4 * h + 3];
      float d = acc[4 * h][r] * avd[4 * h] + acc[4 * h + 1][r] * avd[4 * h + 1] +
                acc[4 * h + 2][r] * avd[4 * h + 2] + acc[4 * h + 3][r] * avd[4 * h + 3];
#pragma unroll
      for (int off = 8; off; off >>= 1) {   // 16-lane group reduce
        s += __shfl_xor(s, off);
        d += __shfl_xor(d, off);
      }
      if (li == 0) {
        int row = row0 + g * 4 + r;
        asrc[row * 3 + h] = s;
        adst[row * 3 + h] = d;
      }
    }
}

// ---------------- fused segment-softmax + aggregation, one wave per node ----------------
template<bool RELU, typename OutT>
__global__ __launch_bounds__(256) void k_aggregate(
    const float* __restrict__ xw, const float* __restrict__ asrc,
    const float* __restrict__ adst, const int* __restrict__ rowptr,
    const int* __restrict__ deg, const int* __restrict__ csr_src,
    const float* __restrict__ bias, OutT* __restrict__ out, int Nn) {
  int wid = threadIdx.x >> 6, lane = threadIdx.x & 63;
  int n = blockIdx.x * 4 + wid;
  if (n >= Nn) return;
  int row = rowptr[n], d = deg[n];
  float ad0 = adst[n * 3], ad1 = adst[n * 3 + 1], ad2 = adst[n * 3 + 2];
  float sa0 = lrelu(asrc[n * 3] + ad0);       // self-loop alpha
  float sa1 = lrelu(asrc[n * 3 + 1] + ad1);
  float sa2 = lrelu(asrc[n * 3 + 2] + ad2);

  float acc0, acc1, acc2, S0, S1, S2;

  if (d <= 64) {
    // fast path: lane e owns edge e; alpha computed exactly once per edge
    int s = 0;
    float al0 = -INFINITY, al1 = -INFINITY, al2 = -INFINITY;
    if (lane < d) {
      s = csr_src[row + lane];
      al0 = lrelu(asrc[s * 3] + ad0);
      al1 = lrelu(asrc[s * 3 + 1] + ad1);
      al2 = lrelu(asrc[s * 3 + 2] + ad2);
    }
    float m0 = fmaxf(wred_max(al0), sa0);
    float m1 = fmaxf(wred_max(al1), sa1);
    float m2 = fmaxf(wred_max(al2), sa2);
    float w0 = __expf(al0 - m0);   // inactive lanes: exp(-inf)=0
    float w1 = __expf(al1 - m1);
    float w2 = __expf(al2 - m2);
    float e0 = __expf(sa0 - m0), e1 = __expf(sa1 - m1), e2 = __expf(sa2 - m2);
    S0 = wred_sum(w0) + e0 + 1e-16f;
    S1 = wred_sum(w1) + e1 + 1e-16f;
    S2 = wred_sum(w2) + e2 + 1e-16f;
    // weighted gather: lane = channel, broadcast edge weight/src via shfl
    const float* xrs = xw + (size_t)n * NC;
    acc0 = e0 * xrs[lane];
    acc1 = e1 * xrs[64 + lane];
    acc2 = e2 * xrs[128 + lane];
    for (int e = 0; e < d; ++e) {
      int se = __shfl(s, e);
      float we0 = __shfl(w0, e), we1 = __shfl(w1, e), we2 = __shfl(w2, e);
      const float* xr = xw + (size_t)se * NC;
      acc0 += we0 * xr[lane];
      acc1 += we1 * xr[64 + lane];
      acc2 += we2 * xr[128 + lane];
    }
  } else {
    // slow path (d > 64): 3-pass, lane-strided
    float m0 = sa0, m1 = sa1, m2 = sa2;
    for (int e = lane; e < d; e += 64) {
      int s = csr_src[row + e];
      m0 = fmaxf(m0, lrelu(asrc[s * 3] + ad0));
      m1 = fmaxf(m1, lrelu(asrc[s * 3 + 1] + ad1));
      m2 = fmaxf(m2, lrelu(asrc[s * 3 + 2] + ad2));
    }
    m0 = wred_max(m0); m1 = wred_max(m1); m2 = wred_max(m2);
    float p0 = 0.f, p1 = 0.f, p2 = 0.f;
    for (int e = lane; e < d; e += 64) {
      int s = csr_src[row + e];
      p0 += __expf(lrelu(asrc[s * 3] + ad0) - m0);
      p1 += __expf(lrelu(asrc[s * 3 + 1] + ad1) - m1);
      p2 += __expf(lrelu(asrc[s * 3 + 2] + ad2) - m2);
    }
    S0 = wred_sum(p0) + __expf(sa0 - m0) + 1e-16f;
    S1 = wred_sum(p1) + __expf(sa1 - m1) + 1e-16f;
    S2 = wred_sum(p2) + __expf(sa2 - m2) + 1e-16f;
    const float* xrs = xw + (size_t)n * NC;
    acc0 = __expf(sa0 - m0) * xrs[lane];
    acc1 = __expf(sa1 - m1) * xrs[64 + lane];
    acc2 = __expf(sa2 - m2) * xrs[128 + lane];
    for (int e = 0; e < d; ++e) {
      int s = csr_src[row + e];
      float we0 = __expf(lrelu(asrc[s * 3] + ad0) - m0);
      float we1 = __expf(lrelu(asrc[s * 3 + 1] + ad1) - m1);
      float we2 = __expf(lrelu(asrc[s * 3 + 2] + ad2) - m2);
      const float* xr = xw + (size_t)s * NC;
      acc0 += we0 * xr[lane];
      acc1 += we1 * xr[64 + lane];
      acc2 += we2 * xr[128 + lane];
    }
  }

  float o = (acc0 / S0 + acc1 / S1 + acc2 / S2) * (1.f / 3.f) + bias[lane];
  out[(size_t)n * CC + lane] = (OutT)(RELU ? fmaxf(o, 0.f) : o);
}

// ---------------- final linear: logit[N,16] = h[N,64] @ Wl[64,16] + bl ----------------
__global__ void k_logit(const float* __restrict__ h, const float* __restrict__ Wl,
                        const float* __restrict__ bl, float* __restrict__ out, int Nn) {
  __shared__ float wl_s[CC * DOUTK];
  __shared__ float hrow[4][CC];
  int tid = threadIdx.x;
  for (int i = tid; i < CC * DOUTK; i += 256) wl_s[i] = Wl[i];
  int wid = tid >> 6, lane = tid & 63;
  int n = blockIdx.x * 4 + wid;
  if (n < Nn) hrow[wid][lane] = h[(size_t)n * CC + lane];
  __syncthreads();
  if (n < Nn && lane < DOUTK) {
    float acc = bl[lane];
#pragma unroll
    for (int c = 0; c < CC; ++c) acc += hrow[wid][c] * wl_s[c * DOUTK + lane];
    out[(size_t)n * DOUTK + lane] = acc;
  }
}

extern "C" void kernel_launch(void* const* d_in, const int* in_sizes, int n_in,
                              void* d_out, int out_size, void* d_ws, size_t ws_size,
                              hipStream_t stream) {
  const float* x   = (const float*)d_in[0];
  const float* W1  = (const float*)d_in[1];
  const float* as1 = (const float*)d_in[2];
  const float* ad1 = (const float*)d_in[3];
  const float* b1  = (const float*)d_in[4];
  const float* W2  = (const float*)d_in[5];
  const float* as2 = (const float*)d_in[6];
  const float* ad2 = (const float*)d_in[7];
  const float* b2  = (const float*)d_in[8];
  const float* Wl  = (const float*)d_in[9];
  const float* bl  = (const float*)d_in[10];
  const int* edges = (const int*)d_in[11];

  const int Nn = in_sizes[0] / 256;   // 50000
  const int E  = in_sizes[11] / 2;    // 800000
  const int* srcs = edges;
  const int* dsts = edges + E;

  float* out_logit = (float*)d_out;                       // [N,16]
  float* out_h     = (float*)d_out + (size_t)Nn * DOUTK;  // [N,64]

  char* p = (char*)d_ws;
  auto alloc = [&](size_t bytes) {
    char* r = p;
    p += (bytes + 255) & ~(size_t)255;
    return r;
  };
  float* xw      = (float*)alloc((size_t)Nn * NC * 4);
  _Float16* xh   = (_Float16*)alloc((size_t)Nn * 256 * 2);  // fp16 x; later aliased-free
  _Float16* h1h  = (_Float16*)alloc((size_t)Nn * CC * 2);   // fp16 layer-1 output
  _Float16* wT1  = (_Float16*)alloc((size_t)NC * 256 * 2);
  _Float16* wT2  = (_Float16*)alloc((size_t)NC * CC * 2);
  float* asrc    = (float*)alloc((size_t)Nn * 3 * 4);
  float* adst    = (float*)alloc((size_t)Nn * 3 * 4);
  int* deg       = (int*)alloc((size_t)Nn * 4);
  int* rowptr    = (int*)alloc((size_t)Nn * 4);
  int* cursor    = (int*)alloc((size_t)Nn * 4);
  int* bsum      = (int*)alloc(256 * 4);
  int* csr_src   = (int*)alloc((size_t)E * 4);

  const int nB = (Nn + 255) / 256;   // 196 (<=256 required by k_scan_bsum)
  const int eB = (E + 255) / 256;
  const int gB = (Nn + 63) / 64;
  const int aB = (Nn + 3) / 4;

  // CSR build (ws is re-poisoned every call -> rebuild everything)
  hipMemsetAsync(deg, 0, (size_t)Nn * 4, stream);
  k_hist<<<eB, 256, 0, stream>>>(dsts, deg, E);
  k_scan_block<<<nB, 256, 0, stream>>>(deg, rowptr, bsum, Nn);
  k_scan_bsum<<<1, 256, 0, stream>>>(bsum, nB);
  k_add_off<<<nB, 256, 0, stream>>>(rowptr, bsum, cursor, Nn);
  k_scatter<<<eB, 256, 0, stream>>>(srcs, dsts, cursor, csr_src, E);

  // dtype prep
  const int nx4 = Nn * 256 / 4;
  k_f2h<<<(nx4 + 255) / 256, 256, 0, stream>>>(x, xh, nx4);
  k_wT<<<(NC * 256 + 255) / 256, 256, 0, stream>>>(W1, wT1, 256);
  k_wT<<<(NC * CC + 255) / 256, 256, 0, stream>>>(W2, wT2, CC);

  // layer 1
  k_gemm_mfma_att<256><<<gB, 256, 0, stream>>>(xh, wT1, as1, ad1, xw, asrc, adst, Nn);
  k_aggregate<true, _Float16><<<aB, 256, 0, stream>>>(xw, asrc, adst, rowptr, deg,
                                                      csr_src, b1, h1h, Nn);

  // layer 2
  k_gemm_mfma_att<64><<<gB, 256, 0, stream>>>(h1h, wT2, as2, ad2, xw, asrc, adst, Nn);
  k_aggregate<false, float><<<aB, 256, 0, stream>>>(xw, asrc, adst, rowptr, deg,
                                                    csr_src, b2, out_h, Nn);

  // final linear
  k_logit<<<aB, 256, 0, stream>>>(out_h, Wl, bl, out_logit, Nn);
}

// Round 5
// 404.969 us; speedup vs baseline: 1.4931x; 1.2496x over previous
//
#include <hip/hip_runtime.h>
#include <cmath>

#define NC 192   // H*C
#define CC 64
#define DOUTK 16

typedef _Float16 f16x8 __attribute__((ext_vector_type(8)));
typedef _Float16 f16x4 __attribute__((ext_vector_type(4)));
typedef float f32x4 __attribute__((ext_vector_type(4)));

__device__ __forceinline__ float lrelu(float x) { return x > 0.f ? x : 0.2f * x; }

__device__ __forceinline__ float wred_sum(float v) {
#pragma unroll
  for (int off = 32; off; off >>= 1) v += __shfl_xor(v, off);
  return v;
}
__device__ __forceinline__ float wred_max(float v) {
#pragma unroll
  for (int off = 32; off; off >>= 1) v = fmaxf(v, __shfl_xor(v, off));
  return v;
}

// ---------------- CSR build (dst-sorted) ----------------
__global__ void k_hist(const int* __restrict__ dsts, int* __restrict__ deg, int E) {
  int e = blockIdx.x * 256 + threadIdx.x;
  if (e < E) atomicAdd(&deg[dsts[e]], 1);
}

__global__ void k_scan_block(const int* __restrict__ deg, int* __restrict__ rowptr,
                             int* __restrict__ bsum, int Nn) {
  __shared__ int tmp[256];
  int i = blockIdx.x * 256 + threadIdx.x;
  int v = (i < Nn) ? deg[i] : 0;
  tmp[threadIdx.x] = v;
  __syncthreads();
  for (int off = 1; off < 256; off <<= 1) {
    int t = (threadIdx.x >= off) ? tmp[threadIdx.x - off] : 0;
    __syncthreads();
    tmp[threadIdx.x] += t;
    __syncthreads();
  }
  if (i < Nn) rowptr[i] = tmp[threadIdx.x] - v;   // exclusive
  if (threadIdx.x == 255) bsum[blockIdx.x] = tmp[255];
}

__global__ void k_scan_bsum(int* __restrict__ bsum, int B) {
  __shared__ int tmp[256];
  int v = (threadIdx.x < B) ? bsum[threadIdx.x] : 0;
  tmp[threadIdx.x] = v;
  __syncthreads();
  for (int off = 1; off < 256; off <<= 1) {
    int t = (threadIdx.x >= off) ? tmp[threadIdx.x - off] : 0;
    __syncthreads();
    tmp[threadIdx.x] += t;
    __syncthreads();
  }
  if (threadIdx.x < B) bsum[threadIdx.x] = tmp[threadIdx.x] - v;  // exclusive
}

__global__ void k_add_off(int* __restrict__ rowptr, const int* __restrict__ bsum,
                          int* __restrict__ cursor, int Nn) {
  int i = blockIdx.x * 256 + threadIdx.x;
  if (i < Nn) {
    int r = rowptr[i] + bsum[blockIdx.x];
    rowptr[i] = r;
    cursor[i] = r;
  }
}

__global__ void k_scatter(const int* __restrict__ srcs, const int* __restrict__ dsts,
                          int* __restrict__ cursor, int* __restrict__ csr_src, int E) {
  int e = blockIdx.x * 256 + threadIdx.x;
  if (e < E) {
    int d = dsts[e];
    int p = atomicAdd(&cursor[d], 1);
    csr_src[p] = srcs[e];
  }
}

// ---------------- dtype conversion ----------------
__global__ void k_f2h(const float* __restrict__ in, _Float16* __restrict__ out, int n4) {
  int i = blockIdx.x * 256 + threadIdx.x;
  if (i < n4) {
    float4 v = *(const float4*)(in + (size_t)i * 4);
    f16x4 o;
    o[0] = (_Float16)v.x; o[1] = (_Float16)v.y;
    o[2] = (_Float16)v.z; o[3] = (_Float16)v.w;
    *(f16x4*)(out + (size_t)i * 4) = o;
  }
}

// W[K][192] fp32 -> WT[192][K] fp16
__global__ void k_wT(const float* __restrict__ W, _Float16* __restrict__ WT, int K) {
  int i = blockIdx.x * 256 + threadIdx.x;
  if (i < NC * K) {
    int c = i / K, k = i - c * K;
    WT[i] = (_Float16)W[(size_t)k * NC + c];
  }
}

// ---------------- LDS-staged MFMA GEMM + fused attention scores ----------------
// XW[M,192](f16) = A[M,K](f16) @ WT[192,K]^T. Block = 256 thr = 4 waves, 128 rows.
// Wave wv: rows wv*32..wv*32+31 (2 m-tiles), all 192 cols (12 n-tiles), KC=32 chunks,
// double-buffered LDS. Row stride 40 f16 (80 B): frag-read bank groups (row*20+g*4)%32
// cycle all 8 16B-groups over 8 rows -> conflict-free b128 reads.
// mfma_f32_16x16x32_f16; A frag row=li k=g*8; D: col=li, row=g*4+reg (m89).
template<int K>
__global__ __launch_bounds__(256) void k_gemm_mfma_att(
    const _Float16* __restrict__ A, const _Float16* __restrict__ WT,
    const float* __restrict__ att_src, const float* __restrict__ att_dst,
    _Float16* __restrict__ XW, float* __restrict__ asrc, float* __restrict__ adst,
    int M) {
  constexpr int KC = 32;
  constexpr int NCHUNK = K / KC;
  constexpr int AST = 40;                     // padded row stride (fp16)
  __shared__ _Float16 As[2][128][AST];
  __shared__ _Float16 Bs[2][192][AST];
  const int tid = threadIdx.x;
  const int lane = tid & 63, wv = tid >> 6;
  const int li = lane & 15, g = lane >> 4;
  const int row0 = blockIdx.x * 128;
  const int srow = tid >> 2, sseg = tid & 3;  // staging: 4 thr x 16B cover one 64B row-chunk

  f32x4 acc0[12], acc1[12];
#pragma unroll
  for (int t = 0; t < 12; ++t) {
    acc0[t] = (f32x4){0.f, 0.f, 0.f, 0.f};
    acc1[t] = (f32x4){0.f, 0.f, 0.f, 0.f};
  }

  const int ra0 = (row0 + srow      < M) ? row0 + srow      : M - 1;  // clamp tail
  const int ra1 = (row0 + 64 + srow < M) ? row0 + 64 + srow : M - 1;

  f16x8 a_st[2], b_st[3];
  auto stage_load = [&](int c) {
    const size_t ko = (size_t)c * KC + sseg * 8;
    a_st[0] = *(const f16x8*)(A + (size_t)ra0 * K + ko);
    a_st[1] = *(const f16x8*)(A + (size_t)ra1 * K + ko);
    b_st[0] = *(const f16x8*)(WT + (size_t)(srow)       * K + ko);
    b_st[1] = *(const f16x8*)(WT + (size_t)(64 + srow)  * K + ko);
    b_st[2] = *(const f16x8*)(WT + (size_t)(128 + srow) * K + ko);
  };
  auto stage_write = [&](int buf) {
    *(f16x8*)&As[buf][srow][sseg * 8]       = a_st[0];
    *(f16x8*)&As[buf][64 + srow][sseg * 8]  = a_st[1];
    *(f16x8*)&Bs[buf][srow][sseg * 8]       = b_st[0];
    *(f16x8*)&Bs[buf][64 + srow][sseg * 8]  = b_st[1];
    *(f16x8*)&Bs[buf][128 + srow][sseg * 8] = b_st[2];
  };

  stage_load(0);
  stage_write(0);
  __syncthreads();

  for (int c = 0; c < NCHUNK; ++c) {
    const int buf = c & 1;
    if (c + 1 < NCHUNK) stage_load(c + 1);
    f16x8 bf[12];
#pragma unroll
    for (int t = 0; t < 12; ++t) bf[t] = *(const f16x8*)&Bs[buf][t * 16 + li][g * 8];
    f16x8 af0 = *(const f16x8*)&As[buf][wv * 32 + li][g * 8];
    f16x8 af1 = *(const f16x8*)&As[buf][wv * 32 + 16 + li][g * 8];
#pragma unroll
    for (int t = 0; t < 12; ++t) {
      acc0[t] = __builtin_amdgcn_mfma_f32_16x16x32_f16(af0, bf[t], acc0[t], 0, 0, 0);
      acc1[t] = __builtin_amdgcn_mfma_f32_16x16x32_f16(af1, bf[t], acc1[t], 0, 0, 0);
    }
    if (c + 1 < NCHUNK) stage_write((c + 1) & 1);
    __syncthreads();
  }

  // epilogue: fp16 XW store + fused attention scores
  float avs[12], avd[12];
#pragma unroll
  for (int t = 0; t < 12; ++t) {
    avs[t] = att_src[t * 16 + li];
    avd[t] = att_dst[t * 16 + li];
  }
#pragma unroll
  for (int mt = 0; mt < 2; ++mt) {
    const f32x4* acc = mt ? acc1 : acc0;
    const int rbase = row0 + wv * 32 + mt * 16 + g * 4;
#pragma unroll
    for (int r = 0; r < 4; ++r) {
      const int row = rbase + r;
      const bool ok = row < M;
#pragma unroll
      for (int t = 0; t < 12; ++t)
        if (ok) XW[(size_t)row * NC + t * 16 + li] = (_Float16)acc[t][r];
#pragma unroll
      for (int h = 0; h < 3; ++h) {
        float s = acc[4*h][r]*avs[4*h] + acc[4*h+1][r]*avs[4*h+1] +
                  acc[4*h+2][r]*avs[4*h+2] + acc[4*h+3][r]*avs[4*h+3];
        float d = acc[4*h][r]*avd[4*h] + acc[4*h+1][r]*avd[4*h+1] +
                  acc[4*h+2][r]*avd[4*h+2] + acc[4*h+3][r]*avd[4*h+3];
#pragma unroll
        for (int off = 8; off; off >>= 1) {
          s += __shfl_xor(s, off);
          d += __shfl_xor(d, off);
        }
        if (ok && li == 0) {
          asrc[row * 3 + h] = s;
          adst[row * 3 + h] = d;
        }
      }
    }
  }
}

// ---------------- fused segment-softmax + aggregation, one wave per node ----------------
template<bool RELU, typename OutT>
__global__ __launch_bounds__(256) void k_aggregate(
    const _Float16* __restrict__ xw, const float* __restrict__ asrc,
    const float* __restrict__ adst, const int* __restrict__ rowptr,
    const int* __restrict__ deg, const int* __restrict__ csr_src,
    const float* __restrict__ bias, OutT* __restrict__ out, int Nn) {
  int wid = threadIdx.x >> 6, lane = threadIdx.x & 63;
  int n = blockIdx.x * 4 + wid;
  if (n >= Nn) return;
  int row = rowptr[n], d = deg[n];
  float ad0 = adst[n * 3], ad1 = adst[n * 3 + 1], ad2 = adst[n * 3 + 2];
  float sa0 = lrelu(asrc[n * 3] + ad0);       // self-loop alpha
  float sa1 = lrelu(asrc[n * 3 + 1] + ad1);
  float sa2 = lrelu(asrc[n * 3 + 2] + ad2);

  float acc0, acc1, acc2, S0, S1, S2;

  if (d <= 64) {
    // fast path: lane e owns edge e; alpha computed exactly once per edge
    int s = 0;
    float al0 = -INFINITY, al1 = -INFINITY, al2 = -INFINITY;
    if (lane < d) {
      s = csr_src[row + lane];
      al0 = lrelu(asrc[s * 3] + ad0);
      al1 = lrelu(asrc[s * 3 + 1] + ad1);
      al2 = lrelu(asrc[s * 3 + 2] + ad2);
    }
    float m0 = fmaxf(wred_max(al0), sa0);
    float m1 = fmaxf(wred_max(al1), sa1);
    float m2 = fmaxf(wred_max(al2), sa2);
    float w0 = __expf(al0 - m0);   // inactive lanes: exp(-inf)=0
    float w1 = __expf(al1 - m1);
    float w2 = __expf(al2 - m2);
    float e0 = __expf(sa0 - m0), e1 = __expf(sa1 - m1), e2 = __expf(sa2 - m2);
    S0 = wred_sum(w0) + e0 + 1e-16f;
    S1 = wred_sum(w1) + e1 + 1e-16f;
    S2 = wred_sum(w2) + e2 + 1e-16f;
    // weighted gather: lane = channel, broadcast edge weight/src via shfl
    const _Float16* xrs = xw + (size_t)n * NC;
    acc0 = e0 * (float)xrs[lane];
    acc1 = e1 * (float)xrs[64 + lane];
    acc2 = e2 * (float)xrs[128 + lane];
    for (int e = 0; e < d; ++e) {
      int se = __shfl(s, e);
      float we0 = __shfl(w0, e), we1 = __shfl(w1, e), we2 = __shfl(w2, e);
      const _Float16* xr = xw + (size_t)se * NC;
      acc0 += we0 * (float)xr[lane];
      acc1 += we1 * (float)xr[64 + lane];
      acc2 += we2 * (float)xr[128 + lane];
    }
  } else {
    // slow path (d > 64): 3-pass, lane-strided
    float m0 = sa0, m1 = sa1, m2 = sa2;
    for (int e = lane; e < d; e += 64) {
      int s = csr_src[row + e];
      m0 = fmaxf(m0, lrelu(asrc[s * 3] + ad0));
      m1 = fmaxf(m1, lrelu(asrc[s * 3 + 1] + ad1));
      m2 = fmaxf(m2, lrelu(asrc[s * 3 + 2] + ad2));
    }
    m0 = wred_max(m0); m1 = wred_max(m1); m2 = wred_max(m2);
    float p0 = 0.f, p1 = 0.f, p2 = 0.f;
    for (int e = lane; e < d; e += 64) {
      int s = csr_src[row + e];
      p0 += __expf(lrelu(asrc[s * 3] + ad0) - m0);
      p1 += __expf(lrelu(asrc[s * 3 + 1] + ad1) - m1);
      p2 += __expf(lrelu(asrc[s * 3 + 2] + ad2) - m2);
    }
    S0 = wred_sum(p0) + __expf(sa0 - m0) + 1e-16f;
    S1 = wred_sum(p1) + __expf(sa1 - m1) + 1e-16f;
    S2 = wred_sum(p2) + __expf(sa2 - m2) + 1e-16f;
    const _Float16* xrs = xw + (size_t)n * NC;
    acc0 = __expf(sa0 - m0) * (float)xrs[lane];
    acc1 = __expf(sa1 - m1) * (float)xrs[64 + lane];
    acc2 = __expf(sa2 - m2) * (float)xrs[128 + lane];
    for (int e = 0; e < d; ++e) {
      int s = csr_src[row + e];
      float we0 = __expf(lrelu(asrc[s * 3] + ad0) - m0);
      float we1 = __expf(lrelu(asrc[s * 3 + 1] + ad1) - m1);
      float we2 = __expf(lrelu(asrc[s * 3 + 2] + ad2) - m2);
      const _Float16* xr = xw + (size_t)s * NC;
      acc0 += we0 * (float)xr[lane];
      acc1 += we1 * (float)xr[64 + lane];
      acc2 += we2 * (float)xr[128 + lane];
    }
  }

  float o = (acc0 / S0 + acc1 / S1 + acc2 / S2) * (1.f / 3.f) + bias[lane];
  out[(size_t)n * CC + lane] = (OutT)(RELU ? fmaxf(o, 0.f) : o);
}

// ---------------- final linear: logit[N,16] = h[N,64] @ Wl[64,16] + bl ----------------
__global__ void k_logit(const float* __restrict__ h, const float* __restrict__ Wl,
                        const float* __restrict__ bl, float* __restrict__ out, int Nn) {
  __shared__ float wl_s[CC * DOUTK];
  __shared__ float hrow[4][CC];
  int tid = threadIdx.x;
  for (int i = tid; i < CC * DOUTK; i += 256) wl_s[i] = Wl[i];
  int wid = tid >> 6, lane = tid & 63;
  int n = blockIdx.x * 4 + wid;
  if (n < Nn) hrow[wid][lane] = h[(size_t)n * CC + lane];
  __syncthreads();
  if (n < Nn && lane < DOUTK) {
    float acc = bl[lane];
#pragma unroll
    for (int c = 0; c < CC; ++c) acc += hrow[wid][c] * wl_s[c * DOUTK + lane];
    out[(size_t)n * DOUTK + lane] = acc;
  }
}

extern "C" void kernel_launch(void* const* d_in, const int* in_sizes, int n_in,
                              void* d_out, int out_size, void* d_ws, size_t ws_size,
                              hipStream_t stream) {
  const float* x   = (const float*)d_in[0];
  const float* W1  = (const float*)d_in[1];
  const float* as1 = (const float*)d_in[2];
  const float* ad1 = (const float*)d_in[3];
  const float* b1  = (const float*)d_in[4];
  const float* W2  = (const float*)d_in[5];
  const float* as2 = (const float*)d_in[6];
  const float* ad2 = (const float*)d_in[7];
  const float* b2  = (const float*)d_in[8];
  const float* Wl  = (const float*)d_in[9];
  const float* bl  = (const float*)d_in[10];
  const int* edges = (const int*)d_in[11];

  const int Nn = in_sizes[0] / 256;   // 50000
  const int E  = in_sizes[11] / 2;    // 800000
  const int* srcs = edges;
  const int* dsts = edges + E;

  float* out_logit = (float*)d_out;                       // [N,16]
  float* out_h     = (float*)d_out + (size_t)Nn * DOUTK;  // [N,64]

  char* p = (char*)d_ws;
  auto alloc = [&](size_t bytes) {
    char* r = p;
    p += (bytes + 255) & ~(size_t)255;
    return r;
  };
  _Float16* xw   = (_Float16*)alloc((size_t)Nn * NC * 2);   // fp16 XW (gather source)
  _Float16* xh   = (_Float16*)alloc((size_t)Nn * 256 * 2);  // fp16 x
  _Float16* h1h  = (_Float16*)alloc((size_t)Nn * CC * 2);   // fp16 layer-1 output
  _Float16* wT1  = (_Float16*)alloc((size_t)NC * 256 * 2);
  _Float16* wT2  = (_Float16*)alloc((size_t)NC * CC * 2);
  float* asrc    = (float*)alloc((size_t)Nn * 3 * 4);
  float* adst    = (float*)alloc((size_t)Nn * 3 * 4);
  int* deg       = (int*)alloc((size_t)Nn * 4);
  int* rowptr    = (int*)alloc((size_t)Nn * 4);
  int* cursor    = (int*)alloc((size_t)Nn * 4);
  int* bsum      = (int*)alloc(256 * 4);
  int* csr_src   = (int*)alloc((size_t)E * 4);

  const int nB = (Nn + 255) / 256;   // 196 (<=256 required by k_scan_bsum)
  const int eB = (E + 255) / 256;
  const int gB = (Nn + 127) / 128;
  const int aB = (Nn + 3) / 4;

  // CSR build (ws is re-poisoned every call -> rebuild everything)
  hipMemsetAsync(deg, 0, (size_t)Nn * 4, stream);
  k_hist<<<eB, 256, 0, stream>>>(dsts, deg, E);
  k_scan_block<<<nB, 256, 0, stream>>>(deg, rowptr, bsum, Nn);
  k_scan_bsum<<<1, 256, 0, stream>>>(bsum, nB);
  k_add_off<<<nB, 256, 0, stream>>>(rowptr, bsum, cursor, Nn);
  k_scatter<<<eB, 256, 0, stream>>>(srcs, dsts, cursor, csr_src, E);

  // dtype prep
  const int nx4 = Nn * 256 / 4;
  k_f2h<<<(nx4 + 255) / 256, 256, 0, stream>>>(x, xh, nx4);
  k_wT<<<(NC * 256 + 255) / 256, 256, 0, stream>>>(W1, wT1, 256);
  k_wT<<<(NC * CC + 255) / 256, 256, 0, stream>>>(W2, wT2, CC);

  // layer 1
  k_gemm_mfma_att<256><<<gB, 256, 0, stream>>>(xh, wT1, as1, ad1, xw, asrc, adst, Nn);
  k_aggregate<true, _Float16><<<aB, 256, 0, stream>>>(xw, asrc, adst, rowptr, deg,
                                                      csr_src, b1, h1h, Nn);

  // layer 2
  k_gemm_mfma_att<64><<<gB, 256, 0, stream>>>(h1h, wT2, as2, ad2, xw, asrc, adst, Nn);
  k_aggregate<false, float><<<aB, 256, 0, stream>>>(xw, asrc, adst, rowptr, deg,
                                                    csr_src, b2, out_h, Nn);

  // final linear
  k_logit<<<aB, 256, 0, stream>>>(out_h, Wl, bl, out_logit, Nn);
}